// Round 7
// baseline (6097.609 us; speedup 1.0000x reference)
//
#include <hip/hip_runtime.h>
#include <hip/hip_bf16.h>
#include <cstdint>

// ---------------------------------------------------------------------------
// GATv2 encoder. Structure per launch:
//   build CSR by dst (histogram -> scan -> scatter)  [shared by both layers]
//   layer: 2x GEMM (xl->bf16, xr->fp32) -> one-wave-per-node aggregate
// GEMM: 64x128 tile, BK=32, 8x4 per-thread accum, transposed X in LDS
//       (A-reads broadcast b128, B-read 4-way b128) -> ~3 LDS ops / 32 FMA.
// Aggregate: lane owns feats {2l,2l+1}; 2-edge unrolled ILP (2 independent
//       gather->shuffle-reduce->exp chains in flight).
// Softmax max-subtraction dropped (cancels algebraically; logits are tiny).
// ---------------------------------------------------------------------------

// ---- GEMM: Y[M,128] = X[M,128] @ W[128,128] + bias ----------------------
template <typename TO>
__global__ __launch_bounds__(256) void gemm_xw(const float* __restrict__ X,
                                               const float* __restrict__ W,
                                               const float* __restrict__ bias,
                                               TO* __restrict__ Y, int M)
{
    __shared__ __align__(16) float XsT[32][72];   // [k][row], pad to 72
    __shared__ __align__(16) float Ws[32][128];   // [k][col]
    const int row0 = blockIdx.x * 64;
    const int tid  = threadIdx.x;
    const int tx   = tid & 31;        // col group: cols tx*4 .. tx*4+3
    const int ty   = tid >> 5;        // row group: rows ty*8 .. ty*8+7

    float acc[8][4] = {};

    for (int kt = 0; kt < 128; kt += 32) {
        // stage X tile transposed: XsT[k][r] = X[row0+r][kt+k]
        {
            const int r  = tid & 63;
            const int kq = tid >> 6;                  // 0..3 (8 k's each)
            const int row = row0 + r;
            float4 v0 = {0,0,0,0}, v1 = {0,0,0,0};
            if (row < M) {
                v0 = *reinterpret_cast<const float4*>(&X[(size_t)row*128 + kt + kq*8]);
                v1 = *reinterpret_cast<const float4*>(&X[(size_t)row*128 + kt + kq*8 + 4]);
            }
            XsT[kq*8+0][r] = v0.x; XsT[kq*8+1][r] = v0.y;
            XsT[kq*8+2][r] = v0.z; XsT[kq*8+3][r] = v0.w;
            XsT[kq*8+4][r] = v1.x; XsT[kq*8+5][r] = v1.y;
            XsT[kq*8+6][r] = v1.z; XsT[kq*8+7][r] = v1.w;
        }
        // stage W tile: Ws[k][c] = W[kt+k][c]
        for (int s = tid; s < 32 * 32; s += 256) {
            const int k = s >> 5, c4 = s & 31;
            *reinterpret_cast<float4*>(&Ws[k][c4*4]) =
                *reinterpret_cast<const float4*>(&W[(size_t)(kt+k)*128 + c4*4]);
        }
        __syncthreads();

        for (int k = 0; k < 32; ++k) {
            const float4 a0 = *reinterpret_cast<const float4*>(&XsT[k][ty*8]);
            const float4 a1 = *reinterpret_cast<const float4*>(&XsT[k][ty*8+4]);
            const float4 b  = *reinterpret_cast<const float4*>(&Ws[k][tx*4]);
            const float ar[8] = {a0.x,a0.y,a0.z,a0.w,a1.x,a1.y,a1.z,a1.w};
#pragma unroll
            for (int i = 0; i < 8; ++i) {
                acc[i][0] += ar[i]*b.x; acc[i][1] += ar[i]*b.y;
                acc[i][2] += ar[i]*b.z; acc[i][3] += ar[i]*b.w;
            }
        }
        __syncthreads();
    }

    const int col = tx * 4;
    const float4 bv = *reinterpret_cast<const float4*>(&bias[col]);
#pragma unroll
    for (int i = 0; i < 8; ++i) {
        const int row = row0 + ty*8 + i;
        if (row < M) {
            const float o0 = acc[i][0]+bv.x, o1 = acc[i][1]+bv.y,
                        o2 = acc[i][2]+bv.z, o3 = acc[i][3]+bv.w;
            if constexpr (__is_same(TO, float)) {
                float4 v = { o0, o1, o2, o3 };
                *reinterpret_cast<float4*>(&Y[(size_t)row*128 + col]) = v;
            } else {   // bf16 output, 4 elems = 8B store
                union { ushort4 u; __hip_bfloat16 b[4]; } pk;
                pk.b[0] = __float2bfloat16(o0);
                pk.b[1] = __float2bfloat16(o1);
                pk.b[2] = __float2bfloat16(o2);
                pk.b[3] = __float2bfloat16(o3);
                *reinterpret_cast<ushort4*>(&Y[(size_t)row*128 + col]) = pk.u;
            }
        }
    }
}

// ---- CSR build ----------------------------------------------------------
__global__ __launch_bounds__(256) void hist_kernel(const int* __restrict__ dst, int E,
                                                   int* __restrict__ count)
{
    for (int i = blockIdx.x * blockDim.x + threadIdx.x; i < E;
         i += gridDim.x * blockDim.x)
        atomicAdd(&count[dst[i]], 1);
}

// single-workgroup exclusive scan of (count[i] + 1)  [+1 = self-loop]
__global__ __launch_bounds__(1024) void scan_offsets(const int* __restrict__ count,
                                                     int* __restrict__ offset,
                                                     int* __restrict__ cursor, int N)
{
    __shared__ int wsum[16];
    __shared__ int carry_s;
    const int tid = threadIdx.x;
    const int lane = tid & 63, w = tid >> 6;
    if (tid == 0) carry_s = 0;
    __syncthreads();
    for (int base = 0; base < N; base += 1024) {
        int i = base + tid;
        int v = (i < N) ? (count[i] + 1) : 0;
        int x = v;
#pragma unroll
        for (int off = 1; off < 64; off <<= 1) {
            int y = __shfl_up(x, off);
            if (lane >= off) x += y;
        }
        if (lane == 63) wsum[w] = x;
        __syncthreads();
        if (tid < 16) {
            int s2 = wsum[tid];
#pragma unroll
            for (int off = 1; off < 16; off <<= 1) {
                int y = __shfl_up(s2, off);
                if (tid >= off) s2 += y;
            }
            wsum[tid] = s2;
        }
        __syncthreads();
        int carry = carry_s;
        int inc = x + ((w > 0) ? wsum[w - 1] : 0) + carry;
        if (i < N) { offset[i] = inc - v; cursor[i] = inc - v; }
        __syncthreads();
        if (tid == 1023) carry_s = inc;
        __syncthreads();
    }
    if (tid == 0) offset[N] = carry_s;
}

__global__ __launch_bounds__(256) void scatter_kernel(const int* __restrict__ src,
                                                      const int* __restrict__ dst, int E,
                                                      int* __restrict__ cursor,
                                                      int* __restrict__ srcids)
{
    for (int i = blockIdx.x * blockDim.x + threadIdx.x; i < E;
         i += gridDim.x * blockDim.x) {
        int p = atomicAdd(&cursor[dst[i]], 1);
        srcids[p] = src[i];
    }
}

__global__ __launch_bounds__(256) void selfloop_kernel(int* __restrict__ cursor,
                                                       int* __restrict__ srcids, int N)
{
    int i = blockIdx.x * blockDim.x + threadIdx.x;
    if (i < N) {
        int p = atomicAdd(&cursor[i], 1);
        srcids[p] = i;
    }
}

// ---- Fused per-node aggregation: one wave per node, 2-edge ILP ----------
// Lane l owns features {2l, 2l+1} (both in head l>>4 when HEADS==4).
template <int HEADS, bool ELU>
__global__ __launch_bounds__(256) void gat_aggregate(
    const uint32_t* __restrict__ xl2,   // [N][64] packed bf16 pairs
    const float* __restrict__ xr,
    const int* __restrict__ offset, const int* __restrict__ srcids,
    const float* __restrict__ att, const float* __restrict__ bias,
    float* __restrict__ out, int N)
{
    const int wid  = (blockIdx.x * blockDim.x + threadIdx.x) >> 6;
    const int lane = threadIdx.x & 63;
    if (wid >= N) return;

    const int f0 = lane * 2;
    const float2 rr = *reinterpret_cast<const float2*>(&xr[(size_t)wid * 128 + f0]);
    const float av0 = att[f0], av1 = att[f0 + 1];

    float acc0 = 0.0f, acc1 = 0.0f, d = 0.0f;
    const int beg = offset[wid], end = offset[wid + 1];

    int i = beg;
    for (; i + 2 <= end; i += 2) {            // two independent chains
        const int sA = srcids[i];
        const int sB = srcids[i + 1];
        const uint32_t vA = xl2[(size_t)sA * 64 + lane];
        const uint32_t vB = xl2[(size_t)sB * 64 + lane];
        const float aA0 = __uint_as_float(vA << 16);
        const float aA1 = __uint_as_float(vA & 0xFFFF0000u);
        const float aB0 = __uint_as_float(vB << 16);
        const float aB1 = __uint_as_float(vB & 0xFFFF0000u);
        float tA0 = aA0 + rr.x, tA1 = aA1 + rr.y;
        float tB0 = aB0 + rr.x, tB1 = aB1 + rr.y;
        tA0 = tA0 > 0.0f ? tA0 : 0.2f * tA0;
        tA1 = tA1 > 0.0f ? tA1 : 0.2f * tA1;
        tB0 = tB0 > 0.0f ? tB0 : 0.2f * tB0;
        tB1 = tB1 > 0.0f ? tB1 : 0.2f * tB1;
        float wA = tA0 * av0 + tA1 * av1;
        float wB = tB0 * av0 + tB1 * av1;
        if (HEADS == 4) {
#pragma unroll
            for (int off = 1; off < 16; off <<= 1) {
                wA += __shfl_xor(wA, off);
                wB += __shfl_xor(wB, off);
            }
        } else {
#pragma unroll
            for (int off = 1; off < 64; off <<= 1) {
                wA += __shfl_xor(wA, off);
                wB += __shfl_xor(wB, off);
            }
        }
        const float pA = __expf(wA);
        const float pB = __expf(wB);
        acc0 += aA0 * pA; acc1 += aA1 * pA; d += pA;
        acc0 += aB0 * pB; acc1 += aB1 * pB; d += pB;
    }
    if (i < end) {                             // tail edge
        const int s = srcids[i];
        const uint32_t v = xl2[(size_t)s * 64 + lane];
        const float a0 = __uint_as_float(v << 16);
        const float a1 = __uint_as_float(v & 0xFFFF0000u);
        float t0 = a0 + rr.x, t1 = a1 + rr.y;
        t0 = t0 > 0.0f ? t0 : 0.2f * t0;
        t1 = t1 > 0.0f ? t1 : 0.2f * t1;
        float w = t0 * av0 + t1 * av1;
        if (HEADS == 4) {
#pragma unroll
            for (int off = 1; off < 16; off <<= 1) w += __shfl_xor(w, off);
        } else {
#pragma unroll
            for (int off = 1; off < 64; off <<= 1) w += __shfl_xor(w, off);
        }
        const float p = __expf(w);
        acc0 += a0 * p; acc1 += a1 * p; d += p;
    }

    float v0 = acc0 / d + bias[f0];
    float v1 = acc1 / d + bias[f0 + 1];
    if (ELU) {
        v0 = v0 > 0.0f ? v0 : expm1f(v0);
        v1 = v1 > 0.0f ? v1 : expm1f(v1);
    }
    float2 o = { v0, v1 };
    *reinterpret_cast<float2*>(&out[(size_t)wid * 128 + f0]) = o;
}

// ---------------------------------------------------------------------------
extern "C" void kernel_launch(void* const* d_in, const int* in_sizes, int n_in,
                              void* d_out, int out_size, void* d_ws, size_t ws_size,
                              hipStream_t stream)
{
    const float* x     = (const float*)d_in[0];
    const int*   ei    = (const int*)  d_in[1];
    const float* W1l   = (const float*)d_in[2];
    const float* b1l   = (const float*)d_in[3];
    const float* W1r   = (const float*)d_in[4];
    const float* b1r   = (const float*)d_in[5];
    const float* att1  = (const float*)d_in[6];
    const float* bias1 = (const float*)d_in[7];
    const float* W2l   = (const float*)d_in[8];
    const float* b2l   = (const float*)d_in[9];
    const float* W2r   = (const float*)d_in[10];
    const float* b2r   = (const float*)d_in[11];
    const float* att2  = (const float*)d_in[12];
    const float* bias2 = (const float*)d_in[13];
    float* out = (float*)d_out;

    const int N    = in_sizes[0] / 128;
    const int E    = in_sizes[1] / 2;
    const int Etot = E + N;
    const int* srcp = ei;         // edge_index[0]
    const int* dstp = ei + E;     // edge_index[1]

    // ---- workspace layout ------------------------------------------------
    int* count  = (int*)d_ws;                 // [N]
    int* offset = count + N;                  // [N+1]
    int* cursor = offset + N + 1;             // [N]
    int* srcids = cursor + N;                 // [Etot]
    size_t int_elems = (size_t)3 * N + 1 + Etot;
    int_elems = (int_elems + 3) & ~(size_t)3;         // 16B align
    float* xr   = (float*)d_ws + int_elems;   // [N*128] f32
    float* hbuf = xr + (size_t)N * 128;       // [N*128] f32
    __hip_bfloat16* xl = (__hip_bfloat16*)(hbuf + (size_t)N * 128);  // [N*128] bf16
    uint32_t* xl2 = (uint32_t*)xl;

    // ---- build CSR by dst (self-loops appended per node) ----
    hipMemsetAsync(count, 0, (size_t)N * sizeof(int), stream);
    hist_kernel<<<2048, 256, 0, stream>>>(dstp, E, count);
    scan_offsets<<<1, 1024, 0, stream>>>(count, offset, cursor, N);
    scatter_kernel<<<2048, 256, 0, stream>>>(srcp, dstp, E, cursor, srcids);
    selfloop_kernel<<<(N + 255) / 256, 256, 0, stream>>>(cursor, srcids, N);

    const int gblocks = (N + 63) / 64;
    const int ablocks = (N + 3) / 4;          // 4 nodes (waves) per block

    // ---- layer 1 ----
    gemm_xw<__hip_bfloat16><<<gblocks, 256, 0, stream>>>(x, W1l, b1l, xl, N);
    gemm_xw<float><<<gblocks, 256, 0, stream>>>(x, W1r, b1r, xr, N);
    gat_aggregate<4, true><<<ablocks, 256, 0, stream>>>(xl2, xr, offset, srcids,
                                                        att1, bias1, hbuf, N);
    // ---- layer 2 ----
    gemm_xw<__hip_bfloat16><<<gblocks, 256, 0, stream>>>(hbuf, W2l, b2l, xl, N);
    gemm_xw<float><<<gblocks, 256, 0, stream>>>(hbuf, W2r, b2r, xr, N);
    gat_aggregate<1, false><<<ablocks, 256, 0, stream>>>(xl2, xr, offset, srcids,
                                                         att2, bias2, out, N);
}

// Round 8
// 643.778 us; speedup vs baseline: 9.4716x; 9.4716x over previous
//
#include <hip/hip_runtime.h>
#include <hip/hip_bf16.h>
#include <cstdint>

// ---------------------------------------------------------------------------
// GATv2 encoder. Structure per launch:
//   build CSR by dst (histogram -> scan -> scatter)  [shared by both layers]
//   layer: 2x GEMM (xl->bf16, xr->fp32) -> one-wave-per-node aggregate
// GEMM: proven 64x64-tile version (R3). NOTE: R6's 64x128/8x4 rewrite spilled
//       (VGPR=256, 2.2GB scratch fetch/dispatch, 60x slower) — do not revisit
//       without -Rpass-analysis first.
// Aggregate: lane owns feats {2l,2l+1}; 2-edge unrolled ILP.
// Softmax max-subtraction dropped (cancels algebraically; logits are tiny).
// ---------------------------------------------------------------------------

// ---- GEMM: Y[M,128] = X[M,128] @ W[128,128] + bias, 64x64 tiles ----------
template <typename TO>
__global__ __launch_bounds__(256) void gemm_xw(const float* __restrict__ X,
                                               const float* __restrict__ W,
                                               const float* __restrict__ bias,
                                               TO* __restrict__ Y, int M)
{
    __shared__ __align__(16) float Xs[64][129];
    __shared__ __align__(16) float Ws[128][64];
    const int bm = blockIdx.x, bn = blockIdx.y;
    const int tid = threadIdx.y * 16 + threadIdx.x;
    const int row0 = bm * 64;

    for (int idx = tid; idx < 64 * 128; idx += 256) {
        int r = idx >> 7, k = idx & 127;
        int row = row0 + r;
        Xs[r][k] = (row < M) ? X[(size_t)row * 128 + k] : 0.0f;
    }
    for (int idx = tid; idx < 128 * 64; idx += 256) {
        int k = idx >> 6, j = idx & 63;
        Ws[k][j] = W[(size_t)k * 128 + bn * 64 + j];
    }
    __syncthreads();

    const int ty = threadIdx.y, tx = threadIdx.x;
    float acc[4][4] = {};
#pragma unroll 8
    for (int k = 0; k < 128; ++k) {
        float4 b = *reinterpret_cast<const float4*>(&Ws[k][tx * 4]);
#pragma unroll
        for (int i = 0; i < 4; ++i) {
            float a = Xs[ty * 4 + i][k];
            acc[i][0] += a * b.x; acc[i][1] += a * b.y;
            acc[i][2] += a * b.z; acc[i][3] += a * b.w;
        }
    }

    const int col = bn * 64 + tx * 4;
    float4 bv = *reinterpret_cast<const float4*>(&bias[col]);
#pragma unroll
    for (int i = 0; i < 4; ++i) {
        int row = row0 + ty * 4 + i;
        if (row < M) {
            float o[4] = { acc[i][0] + bv.x, acc[i][1] + bv.y,
                           acc[i][2] + bv.z, acc[i][3] + bv.w };
            if constexpr (__is_same(TO, float)) {
                float4 v = { o[0], o[1], o[2], o[3] };
                *reinterpret_cast<float4*>(&Y[(size_t)row * 128 + col]) = v;
            } else {   // bf16 output, 4 elems = 8B store
                union { ushort4 u; __hip_bfloat16 b[4]; } pk;
                pk.b[0] = __float2bfloat16(o[0]);
                pk.b[1] = __float2bfloat16(o[1]);
                pk.b[2] = __float2bfloat16(o[2]);
                pk.b[3] = __float2bfloat16(o[3]);
                *reinterpret_cast<ushort4*>(&Y[(size_t)row * 128 + col]) = pk.u;
            }
        }
    }
}

// ---- CSR build ----------------------------------------------------------
__global__ __launch_bounds__(256) void hist_kernel(const int* __restrict__ dst, int E,
                                                   int* __restrict__ count)
{
    for (int i = blockIdx.x * blockDim.x + threadIdx.x; i < E;
         i += gridDim.x * blockDim.x)
        atomicAdd(&count[dst[i]], 1);
}

// single-workgroup exclusive scan of (count[i] + 1)  [+1 = self-loop]
__global__ __launch_bounds__(1024) void scan_offsets(const int* __restrict__ count,
                                                     int* __restrict__ offset,
                                                     int* __restrict__ cursor, int N)
{
    __shared__ int wsum[16];
    __shared__ int carry_s;
    const int tid = threadIdx.x;
    const int lane = tid & 63, w = tid >> 6;
    if (tid == 0) carry_s = 0;
    __syncthreads();
    for (int base = 0; base < N; base += 1024) {
        int i = base + tid;
        int v = (i < N) ? (count[i] + 1) : 0;
        int x = v;
#pragma unroll
        for (int off = 1; off < 64; off <<= 1) {
            int y = __shfl_up(x, off);
            if (lane >= off) x += y;
        }
        if (lane == 63) wsum[w] = x;
        __syncthreads();
        if (tid < 16) {
            int s2 = wsum[tid];
#pragma unroll
            for (int off = 1; off < 16; off <<= 1) {
                int y = __shfl_up(s2, off);
                if (tid >= off) s2 += y;
            }
            wsum[tid] = s2;
        }
        __syncthreads();
        int carry = carry_s;
        int inc = x + ((w > 0) ? wsum[w - 1] : 0) + carry;
        if (i < N) { offset[i] = inc - v; cursor[i] = inc - v; }
        __syncthreads();
        if (tid == 1023) carry_s = inc;
        __syncthreads();
    }
    if (tid == 0) offset[N] = carry_s;
}

__global__ __launch_bounds__(256) void scatter_kernel(const int* __restrict__ src,
                                                      const int* __restrict__ dst, int E,
                                                      int* __restrict__ cursor,
                                                      int* __restrict__ srcids)
{
    for (int i = blockIdx.x * blockDim.x + threadIdx.x; i < E;
         i += gridDim.x * blockDim.x) {
        int p = atomicAdd(&cursor[dst[i]], 1);
        srcids[p] = src[i];
    }
}

__global__ __launch_bounds__(256) void selfloop_kernel(int* __restrict__ cursor,
                                                       int* __restrict__ srcids, int N)
{
    int i = blockIdx.x * blockDim.x + threadIdx.x;
    if (i < N) {
        int p = atomicAdd(&cursor[i], 1);
        srcids[p] = i;
    }
}

// ---- Fused per-node aggregation: one wave per node, 2-edge ILP ----------
// Lane l owns features {2l, 2l+1} (both in head l>>4 when HEADS==4).
template <int HEADS, bool ELU>
__global__ __launch_bounds__(256) void gat_aggregate(
    const uint32_t* __restrict__ xl2,   // [N][64] packed bf16 pairs
    const float* __restrict__ xr,
    const int* __restrict__ offset, const int* __restrict__ srcids,
    const float* __restrict__ att, const float* __restrict__ bias,
    float* __restrict__ out, int N)
{
    const int wid  = (blockIdx.x * blockDim.x + threadIdx.x) >> 6;
    const int lane = threadIdx.x & 63;
    if (wid >= N) return;

    const int f0 = lane * 2;
    const float2 rr = *reinterpret_cast<const float2*>(&xr[(size_t)wid * 128 + f0]);
    const float av0 = att[f0], av1 = att[f0 + 1];

    float acc0 = 0.0f, acc1 = 0.0f, d = 0.0f;
    const int beg = offset[wid], end = offset[wid + 1];

    int i = beg;
    for (; i + 2 <= end; i += 2) {            // two independent chains
        const int sA = srcids[i];
        const int sB = srcids[i + 1];
        const uint32_t vA = xl2[(size_t)sA * 64 + lane];
        const uint32_t vB = xl2[(size_t)sB * 64 + lane];
        const float aA0 = __uint_as_float(vA << 16);
        const float aA1 = __uint_as_float(vA & 0xFFFF0000u);
        const float aB0 = __uint_as_float(vB << 16);
        const float aB1 = __uint_as_float(vB & 0xFFFF0000u);
        float tA0 = aA0 + rr.x, tA1 = aA1 + rr.y;
        float tB0 = aB0 + rr.x, tB1 = aB1 + rr.y;
        tA0 = tA0 > 0.0f ? tA0 : 0.2f * tA0;
        tA1 = tA1 > 0.0f ? tA1 : 0.2f * tA1;
        tB0 = tB0 > 0.0f ? tB0 : 0.2f * tB0;
        tB1 = tB1 > 0.0f ? tB1 : 0.2f * tB1;
        float wA = tA0 * av0 + tA1 * av1;
        float wB = tB0 * av0 + tB1 * av1;
        if (HEADS == 4) {
#pragma unroll
            for (int off = 1; off < 16; off <<= 1) {
                wA += __shfl_xor(wA, off);
                wB += __shfl_xor(wB, off);
            }
        } else {
#pragma unroll
            for (int off = 1; off < 64; off <<= 1) {
                wA += __shfl_xor(wA, off);
                wB += __shfl_xor(wB, off);
            }
        }
        const float pA = __expf(wA);
        const float pB = __expf(wB);
        acc0 += aA0 * pA; acc1 += aA1 * pA; d += pA;
        acc0 += aB0 * pB; acc1 += aB1 * pB; d += pB;
    }
    if (i < end) {                             // tail edge
        const int s = srcids[i];
        const uint32_t v = xl2[(size_t)s * 64 + lane];
        const float a0 = __uint_as_float(v << 16);
        const float a1 = __uint_as_float(v & 0xFFFF0000u);
        float t0 = a0 + rr.x, t1 = a1 + rr.y;
        t0 = t0 > 0.0f ? t0 : 0.2f * t0;
        t1 = t1 > 0.0f ? t1 : 0.2f * t1;
        float w = t0 * av0 + t1 * av1;
        if (HEADS == 4) {
#pragma unroll
            for (int off = 1; off < 16; off <<= 1) w += __shfl_xor(w, off);
        } else {
#pragma unroll
            for (int off = 1; off < 64; off <<= 1) w += __shfl_xor(w, off);
        }
        const float p = __expf(w);
        acc0 += a0 * p; acc1 += a1 * p; d += p;
    }

    float v0 = acc0 / d + bias[f0];
    float v1 = acc1 / d + bias[f0 + 1];
    if (ELU) {
        v0 = v0 > 0.0f ? v0 : expm1f(v0);
        v1 = v1 > 0.0f ? v1 : expm1f(v1);
    }
    float2 o = { v0, v1 };
    *reinterpret_cast<float2*>(&out[(size_t)wid * 128 + f0]) = o;
}

// ---------------------------------------------------------------------------
extern "C" void kernel_launch(void* const* d_in, const int* in_sizes, int n_in,
                              void* d_out, int out_size, void* d_ws, size_t ws_size,
                              hipStream_t stream)
{
    const float* x     = (const float*)d_in[0];
    const int*   ei    = (const int*)  d_in[1];
    const float* W1l   = (const float*)d_in[2];
    const float* b1l   = (const float*)d_in[3];
    const float* W1r   = (const float*)d_in[4];
    const float* b1r   = (const float*)d_in[5];
    const float* att1  = (const float*)d_in[6];
    const float* bias1 = (const float*)d_in[7];
    const float* W2l   = (const float*)d_in[8];
    const float* b2l   = (const float*)d_in[9];
    const float* W2r   = (const float*)d_in[10];
    const float* b2r   = (const float*)d_in[11];
    const float* att2  = (const float*)d_in[12];
    const float* bias2 = (const float*)d_in[13];
    float* out = (float*)d_out;

    const int N    = in_sizes[0] / 128;
    const int E    = in_sizes[1] / 2;
    const int Etot = E + N;
    const int* srcp = ei;         // edge_index[0]
    const int* dstp = ei + E;     // edge_index[1]

    // ---- workspace layout ------------------------------------------------
    int* count  = (int*)d_ws;                 // [N]
    int* offset = count + N;                  // [N+1]
    int* cursor = offset + N + 1;             // [N]
    int* srcids = cursor + N;                 // [Etot]
    size_t int_elems = (size_t)3 * N + 1 + Etot;
    int_elems = (int_elems + 3) & ~(size_t)3;         // 16B align
    float* xr   = (float*)d_ws + int_elems;   // [N*128] f32
    float* hbuf = xr + (size_t)N * 128;       // [N*128] f32
    __hip_bfloat16* xl = (__hip_bfloat16*)(hbuf + (size_t)N * 128);  // [N*128] bf16
    uint32_t* xl2 = (uint32_t*)xl;

    // ---- build CSR by dst (self-loops appended per node) ----
    hipMemsetAsync(count, 0, (size_t)N * sizeof(int), stream);
    hist_kernel<<<2048, 256, 0, stream>>>(dstp, E, count);
    scan_offsets<<<1, 1024, 0, stream>>>(count, offset, cursor, N);
    scatter_kernel<<<2048, 256, 0, stream>>>(srcp, dstp, E, cursor, srcids);
    selfloop_kernel<<<(N + 255) / 256, 256, 0, stream>>>(cursor, srcids, N);

    dim3 gB(16, 16);
    dim3 gG((N + 63) / 64, 2);
    const int ablocks = (N + 3) / 4;          // 4 nodes (waves) per block

    // ---- layer 1 ----
    gemm_xw<__hip_bfloat16><<<gG, gB, 0, stream>>>(x, W1l, b1l, xl, N);
    gemm_xw<float><<<gG, gB, 0, stream>>>(x, W1r, b1r, xr, N);
    gat_aggregate<4, true><<<ablocks, 256, 0, stream>>>(xl2, xr, offset, srcids,
                                                        att1, bias1, hbuf, N);
    // ---- layer 2 ----
    gemm_xw<__hip_bfloat16><<<gG, gB, 0, stream>>>(hbuf, W2l, b2l, xl, N);
    gemm_xw<float><<<gG, gB, 0, stream>>>(hbuf, W2r, b2r, xr, N);
    gat_aggregate<1, false><<<ablocks, 256, 0, stream>>>(xl2, xr, offset, srcids,
                                                         att2, bias2, out, N);
}

// Round 12
// 448.234 us; speedup vs baseline: 13.6036x; 1.4363x over previous
//
#include <hip/hip_runtime.h>
#include <hip/hip_bf16.h>
#include <cstdint>

// ---------------------------------------------------------------------------
// GATv2 encoder. Per launch:
//   convert x->bf16, W*->bf16 transposed; build CSR by dst;
//   layer: 2x MFMA-bf16 GEMM (xl->bf16, xr->fp32) -> one-wave-per-node
//          aggregate (2-edge ILP); agg1 emits h as bf16 (A-operand of L2 GEMM)
// GEMM: 128x64 tile, 4 waves, per-wave 2x4 frags of mfma_f32_16x16x32_bf16
//       (acc=32 VGPR -- R6 lesson: keep per-thread arrays small, no spills).
//       W^T staged in LDS padded to 136 elems/row (272B: conflict-optimal).
// Softmax max-subtraction dropped (cancels algebraically; logits are tiny).
// ---------------------------------------------------------------------------

typedef __attribute__((ext_vector_type(8))) short  bf16x8;
typedef __attribute__((ext_vector_type(4))) float  f32x4;

__device__ inline uint16_t f2bf(float x) {
    union { __hip_bfloat16 b; uint16_t u; } cv;
    cv.b = __float2bfloat16(x);
    return cv.u;
}

// ---- converts -----------------------------------------------------------
__global__ __launch_bounds__(256) void f32_to_bf16(const float* __restrict__ in,
                                                   uint16_t* __restrict__ outp, int n4)
{
    int i = blockIdx.x * blockDim.x + threadIdx.x;
    if (i < n4) {
        float4 v = reinterpret_cast<const float4*>(in)[i];
        ushort4 o = { f2bf(v.x), f2bf(v.y), f2bf(v.z), f2bf(v.w) };
        reinterpret_cast<ushort4*>(outp)[i] = o;
    }
}

// W fp32 [128 k][128 c] -> WT bf16 [128 c][128 k]
__global__ __launch_bounds__(256) void w_to_bf16T(const float* __restrict__ W,
                                                  uint16_t* __restrict__ WT)
{
    int i = blockIdx.x * blockDim.x + threadIdx.x;
    if (i < 128 * 128) {
        int k = i >> 7, c = i & 127;
        WT[c * 128 + k] = f2bf(W[i]);
    }
}

// ---- MFMA GEMM: Y[M,128] = A[M,128](bf16) @ W + bias --------------------
// grid (ceil(M/128), 2); WT = [col][k] bf16.
template <bool OUT_BF16>
__global__ __launch_bounds__(256) void gemm_mfma(
    const uint16_t* __restrict__ A, const uint16_t* __restrict__ WT,
    const float* __restrict__ bias, void* __restrict__ Y, int M)
{
    __shared__ uint16_t WT_lds[64][136];          // 17408 B, pad->272B rows
    const int col0 = blockIdx.y * 64;
    const int row0 = blockIdx.x * 128;
    const int tid  = threadIdx.x;
    const int w    = tid >> 6, l = tid & 63;
    const int cl   = l & 15;
    const int kb   = (l >> 4) * 8;

    // stage W^T tile (64 cols x 128 k), b128 both sides, conflict-free
    for (int i = tid; i < 64 * 16; i += 256) {
        const int c = i >> 4, ch = i & 15;
        const uint4 v = *reinterpret_cast<const uint4*>(&WT[(size_t)(col0 + c) * 128 + ch * 8]);
        *reinterpret_cast<uint4*>(&WT_lds[c][ch * 8]) = v;
    }
    __syncthreads();

    const int mrow = row0 + w * 32 + cl;
    const int rA0 = mrow < M ? mrow : M - 1;           // clamp (tail block)
    const int rA1 = (mrow + 16) < M ? (mrow + 16) : M - 1;
    const uint16_t* a0p = A + (size_t)rA0 * 128 + kb;
    const uint16_t* a1p = A + (size_t)rA1 * 128 + kb;

    f32x4 acc[2][4] = {};
#pragma unroll
    for (int ks = 0; ks < 4; ++ks) {
        const bf16x8 a0 = *reinterpret_cast<const bf16x8*>(a0p + ks * 32);
        const bf16x8 a1 = *reinterpret_cast<const bf16x8*>(a1p + ks * 32);
#pragma unroll
        for (int n = 0; n < 4; ++n) {
            const bf16x8 b = *reinterpret_cast<const bf16x8*>(&WT_lds[n * 16 + cl][ks * 32 + kb]);
            acc[0][n] = __builtin_amdgcn_mfma_f32_16x16x32_bf16(a0, b, acc[0][n], 0, 0, 0);
            acc[1][n] = __builtin_amdgcn_mfma_f32_16x16x32_bf16(a1, b, acc[1][n], 0, 0, 0);
        }
    }

    // C/D: col = lane&15, row = (lane>>4)*4 + j   [m89-verified]
    const int rbase = row0 + w * 32 + (l >> 4) * 4;
#pragma unroll
    for (int m = 0; m < 2; ++m) {
#pragma unroll
        for (int n = 0; n < 4; ++n) {
            const int col = col0 + n * 16 + cl;
            const float bv = bias[col];
#pragma unroll
            for (int j = 0; j < 4; ++j) {
                const int row = rbase + m * 16 + j;
                if (row < M) {
                    const float v = acc[m][n][j] + bv;
                    if constexpr (OUT_BF16)
                        ((uint16_t*)Y)[(size_t)row * 128 + col] = f2bf(v);
                    else
                        ((float*)Y)[(size_t)row * 128 + col] = v;
                }
            }
        }
    }
}

// ---- CSR build ----------------------------------------------------------
__global__ __launch_bounds__(256) void hist_kernel(const int* __restrict__ dst, int E,
                                                   int* __restrict__ count)
{
    for (int i = blockIdx.x * blockDim.x + threadIdx.x; i < E;
         i += gridDim.x * blockDim.x)
        atomicAdd(&count[dst[i]], 1);
}

// single-workgroup exclusive scan of (count[i] + 1)  [+1 = self-loop]
__global__ __launch_bounds__(1024) void scan_offsets(const int* __restrict__ count,
                                                     int* __restrict__ offset,
                                                     int* __restrict__ cursor, int N)
{
    __shared__ int wsum[16];
    __shared__ int carry_s;
    const int tid = threadIdx.x;
    const int lane = tid & 63, w = tid >> 6;
    if (tid == 0) carry_s = 0;
    __syncthreads();
    for (int base = 0; base < N; base += 1024) {
        int i = base + tid;
        int v = (i < N) ? (count[i] + 1) : 0;
        int x = v;
#pragma unroll
        for (int off = 1; off < 64; off <<= 1) {
            int y = __shfl_up(x, off);
            if (lane >= off) x += y;
        }
        if (lane == 63) wsum[w] = x;
        __syncthreads();
        if (tid < 16) {
            int s2 = wsum[tid];
#pragma unroll
            for (int off = 1; off < 16; off <<= 1) {
                int y = __shfl_up(s2, off);
                if (tid >= off) s2 += y;
            }
            wsum[tid] = s2;
        }
        __syncthreads();
        int carry = carry_s;
        int inc = x + ((w > 0) ? wsum[w - 1] : 0) + carry;
        if (i < N) { offset[i] = inc - v; cursor[i] = inc - v; }
        __syncthreads();
        if (tid == 1023) carry_s = inc;
        __syncthreads();
    }
    if (tid == 0) offset[N] = carry_s;
}

__global__ __launch_bounds__(256) void scatter_kernel(const int* __restrict__ src,
                                                      const int* __restrict__ dst, int E,
                                                      int* __restrict__ cursor,
                                                      int* __restrict__ srcids)
{
    for (int i = blockIdx.x * blockDim.x + threadIdx.x; i < E;
         i += gridDim.x * blockDim.x) {
        int p = atomicAdd(&cursor[dst[i]], 1);
        srcids[p] = src[i];
    }
}

__global__ __launch_bounds__(256) void selfloop_kernel(int* __restrict__ cursor,
                                                       int* __restrict__ srcids, int N)
{
    int i = blockIdx.x * blockDim.x + threadIdx.x;
    if (i < N) {
        int p = atomicAdd(&cursor[i], 1);
        srcids[p] = i;
    }
}

// ---- Fused per-node aggregation: one wave per node, 2-edge ILP ----------
// Lane l owns features {2l, 2l+1} (both in head l>>4 when HEADS==4).
// OUT_BF16: pack (v0,v1) into one u32 (bf16 pair) -> feeds next GEMM's A.
template <int HEADS, bool ELU, bool OUT_BF16>
__global__ __launch_bounds__(256) void gat_aggregate(
    const uint32_t* __restrict__ xl2,   // [N][64] packed bf16 pairs
    const float* __restrict__ xr,
    const int* __restrict__ offset, const int* __restrict__ srcids,
    const float* __restrict__ att, const float* __restrict__ bias,
    void* __restrict__ out, int N)
{
    const int wid  = (blockIdx.x * blockDim.x + threadIdx.x) >> 6;
    const int lane = threadIdx.x & 63;
    if (wid >= N) return;

    const int f0 = lane * 2;
    const float2 rr = *reinterpret_cast<const float2*>(&xr[(size_t)wid * 128 + f0]);
    const float av0 = att[f0], av1 = att[f0 + 1];

    float acc0 = 0.0f, acc1 = 0.0f, d = 0.0f;
    const int beg = offset[wid], end = offset[wid + 1];

    int i = beg;
    for (; i + 2 <= end; i += 2) {            // two independent chains
        const int sA = srcids[i];
        const int sB = srcids[i + 1];
        const uint32_t vA = xl2[(size_t)sA * 64 + lane];
        const uint32_t vB = xl2[(size_t)sB * 64 + lane];
        const float aA0 = __uint_as_float(vA << 16);
        const float aA1 = __uint_as_float(vA & 0xFFFF0000u);
        const float aB0 = __uint_as_float(vB << 16);
        const float aB1 = __uint_as_float(vB & 0xFFFF0000u);
        float tA0 = aA0 + rr.x, tA1 = aA1 + rr.y;
        float tB0 = aB0 + rr.x, tB1 = aB1 + rr.y;
        tA0 = tA0 > 0.0f ? tA0 : 0.2f * tA0;
        tA1 = tA1 > 0.0f ? tA1 : 0.2f * tA1;
        tB0 = tB0 > 0.0f ? tB0 : 0.2f * tB0;
        tB1 = tB1 > 0.0f ? tB1 : 0.2f * tB1;
        float wA = tA0 * av0 + tA1 * av1;
        float wB = tB0 * av0 + tB1 * av1;
        if (HEADS == 4) {
#pragma unroll
            for (int off = 1; off < 16; off <<= 1) {
                wA += __shfl_xor(wA, off);
                wB += __shfl_xor(wB, off);
            }
        } else {
#pragma unroll
            for (int off = 1; off < 64; off <<= 1) {
                wA += __shfl_xor(wA, off);
                wB += __shfl_xor(wB, off);
            }
        }
        const float pA = __expf(wA);
        const float pB = __expf(wB);
        acc0 += aA0 * pA; acc1 += aA1 * pA; d += pA;
        acc0 += aB0 * pB; acc1 += aB1 * pB; d += pB;
    }
    if (i < end) {                             // tail edge
        const int s = srcids[i];
        const uint32_t v = xl2[(size_t)s * 64 + lane];
        const float a0 = __uint_as_float(v << 16);
        const float a1 = __uint_as_float(v & 0xFFFF0000u);
        float t0 = a0 + rr.x, t1 = a1 + rr.y;
        t0 = t0 > 0.0f ? t0 : 0.2f * t0;
        t1 = t1 > 0.0f ? t1 : 0.2f * t1;
        float w = t0 * av0 + t1 * av1;
        if (HEADS == 4) {
#pragma unroll
            for (int off = 1; off < 16; off <<= 1) w += __shfl_xor(w, off);
        } else {
#pragma unroll
            for (int off = 1; off < 64; off <<= 1) w += __shfl_xor(w, off);
        }
        const float p = __expf(w);
        acc0 += a0 * p; acc1 += a1 * p; d += p;
    }

    float v0 = acc0 / d + bias[f0];
    float v1 = acc1 / d + bias[f0 + 1];
    if (ELU) {
        v0 = v0 > 0.0f ? v0 : expm1f(v0);
        v1 = v1 > 0.0f ? v1 : expm1f(v1);
    }
    if constexpr (OUT_BF16) {
        const uint32_t pk = (uint32_t)f2bf(v0) | ((uint32_t)f2bf(v1) << 16);
        ((uint32_t*)out)[(size_t)wid * 64 + lane] = pk;
    } else {
        float2 o = { v0, v1 };
        *reinterpret_cast<float2*>(&((float*)out)[(size_t)wid * 128 + f0]) = o;
    }
}

// ---------------------------------------------------------------------------
extern "C" void kernel_launch(void* const* d_in, const int* in_sizes, int n_in,
                              void* d_out, int out_size, void* d_ws, size_t ws_size,
                              hipStream_t stream)
{
    const float* x     = (const float*)d_in[0];
    const int*   ei    = (const int*)  d_in[1];
    const float* W1l   = (const float*)d_in[2];
    const float* b1l   = (const float*)d_in[3];
    const float* W1r   = (const float*)d_in[4];
    const float* b1r   = (const float*)d_in[5];
    const float* att1  = (const float*)d_in[6];
    const float* bias1 = (const float*)d_in[7];
    const float* W2l   = (const float*)d_in[8];
    const float* b2l   = (const float*)d_in[9];
    const float* W2r   = (const float*)d_in[10];
    const float* b2r   = (const float*)d_in[11];
    const float* att2  = (const float*)d_in[12];
    const float* bias2 = (const float*)d_in[13];
    float* out = (float*)d_out;

    const int N    = in_sizes[0] / 128;
    const int E    = in_sizes[1] / 2;
    const int Etot = E + N;
    const int* srcp = ei;         // edge_index[0]
    const int* dstp = ei + E;     // edge_index[1]

    // ---- workspace layout ------------------------------------------------
    int* count  = (int*)d_ws;                 // [N]
    int* offset = count + N;                  // [N+1]
    int* cursor = offset + N + 1;             // [N]
    int* srcids = cursor + N;                 // [Etot]
    size_t int_elems = (size_t)3 * N + 1 + Etot;
    int_elems = (int_elems + 3) & ~(size_t)3;          // 16B align
    uint32_t* base32 = (uint32_t*)d_ws + int_elems;
    uint16_t* x_bf   = (uint16_t*)base32;              // [N*128] bf16
    uint16_t* wt1l   = x_bf + (size_t)N * 128;         // [128*128] each
    uint16_t* wt1r   = wt1l + 128 * 128;
    uint16_t* wt2l   = wt1r + 128 * 128;
    uint16_t* wt2r   = wt2l + 128 * 128;
    float*    xr     = (float*)(wt2r + 128 * 128);     // [N*128] f32
    uint16_t* h_bf   = (uint16_t*)(xr + (size_t)N * 128);  // [N*128] bf16
    uint16_t* xl_bf  = h_bf + (size_t)N * 128;         // [N*128] bf16
    uint32_t* h2  = (uint32_t*)h_bf;
    uint32_t* xl2 = (uint32_t*)xl_bf;

    // ---- converts --------------------------------------------------------
    f32_to_bf16<<<(N * 32 + 255) / 256, 256, 0, stream>>>(x, x_bf, N * 32);
    w_to_bf16T<<<64, 256, 0, stream>>>(W1l, wt1l);
    w_to_bf16T<<<64, 256, 0, stream>>>(W1r, wt1r);
    w_to_bf16T<<<64, 256, 0, stream>>>(W2l, wt2l);
    w_to_bf16T<<<64, 256, 0, stream>>>(W2r, wt2r);

    // ---- build CSR by dst (self-loops appended per node) ----
    hipMemsetAsync(count, 0, (size_t)N * sizeof(int), stream);
    hist_kernel<<<2048, 256, 0, stream>>>(dstp, E, count);
    scan_offsets<<<1, 1024, 0, stream>>>(count, offset, cursor, N);
    scatter_kernel<<<2048, 256, 0, stream>>>(srcp, dstp, E, cursor, srcids);
    selfloop_kernel<<<(N + 255) / 256, 256, 0, stream>>>(cursor, srcids, N);

    dim3 gG((N + 127) / 128, 2);
    const int ablocks = (N + 3) / 4;          // 4 nodes (waves) per block

    // ---- layer 1 ----
    gemm_mfma<true ><<<gG, 256, 0, stream>>>(x_bf, wt1l, b1l, xl_bf, N);
    gemm_mfma<false><<<gG, 256, 0, stream>>>(x_bf, wt1r, b1r, xr,    N);
    gat_aggregate<4, true, true><<<ablocks, 256, 0, stream>>>(
        xl2, xr, offset, srcids, att1, bias1, h_bf, N);
    // ---- layer 2 ----
    gemm_mfma<true ><<<gG, 256, 0, stream>>>(h_bf, wt2l, b2l, xl_bf, N);
    gemm_mfma<false><<<gG, 256, 0, stream>>>(h_bf, wt2r, b2r, xr,    N);
    gat_aggregate<1, false, false><<<ablocks, 256, 0, stream>>>(
        xl2, xr, offset, srcids, att2, bias2, out, N);
}

// Round 13
// 383.985 us; speedup vs baseline: 15.8798x; 1.1673x over previous
//
#include <hip/hip_runtime.h>
#include <hip/hip_bf16.h>
#include <cstdint>

// ---------------------------------------------------------------------------
// GATv2 encoder. Per launch:
//   convert x->bf16, W*->bf16T (one dispatch); CSR by dst via parallel scan;
//   layer: 2x MFMA-bf16 GEMM -> one-wave-per-node aggregate (4-edge ILP)
// GEMM: 128x64 tile, 4 waves, 2x4 frags mfma_f32_16x16x32_bf16 (no spills).
// Scan: 3-kernel parallel (blocksums -> 1-wave mid scan -> apply), replacing
//       the single-workgroup serial scan (latency-bound, ~49 serialized iters).
// Softmax max-subtraction dropped (cancels algebraically; logits are tiny).
// ---------------------------------------------------------------------------

typedef __attribute__((ext_vector_type(8))) short  bf16x8;
typedef __attribute__((ext_vector_type(4))) float  f32x4;

__device__ inline uint16_t f2bf(float x) {
    union { __hip_bfloat16 b; uint16_t u; } cv;
    cv.b = __float2bfloat16(x);
    return cv.u;
}

// ---- converts -----------------------------------------------------------
__global__ __launch_bounds__(256) void f32_to_bf16(const float* __restrict__ in,
                                                   uint16_t* __restrict__ outp, int n4)
{
    int i = blockIdx.x * blockDim.x + threadIdx.x;
    if (i < n4) {
        float4 v = reinterpret_cast<const float4*>(in)[i];
        ushort4 o = { f2bf(v.x), f2bf(v.y), f2bf(v.z), f2bf(v.w) };
        reinterpret_cast<ushort4*>(outp)[i] = o;
    }
}

// all 4 weights fp32 [128 k][128 c] -> WT bf16 [128 c][128 k], one dispatch
__global__ __launch_bounds__(256) void w4_to_bf16T(
    const float* __restrict__ W0, const float* __restrict__ W1,
    const float* __restrict__ W2, const float* __restrict__ W3,
    uint16_t* __restrict__ T0, uint16_t* __restrict__ T1,
    uint16_t* __restrict__ T2, uint16_t* __restrict__ T3)
{
    int i = blockIdx.x * blockDim.x + threadIdx.x;
    const int which = i >> 14, j = i & 16383;
    const int k = j >> 7, c = j & 127;
    const float* W = which == 0 ? W0 : which == 1 ? W1 : which == 2 ? W2 : W3;
    uint16_t*   T = which == 0 ? T0 : which == 1 ? T1 : which == 2 ? T2 : T3;
    T[c * 128 + k] = f2bf(W[j]);
}

// ---- MFMA GEMM: Y[M,128] = A[M,128](bf16) @ W + bias --------------------
template <bool OUT_BF16>
__global__ __launch_bounds__(256) void gemm_mfma(
    const uint16_t* __restrict__ A, const uint16_t* __restrict__ WT,
    const float* __restrict__ bias, void* __restrict__ Y, int M)
{
    __shared__ uint16_t WT_lds[64][136];          // 17408 B, pad->272B rows
    const int col0 = blockIdx.y * 64;
    const int row0 = blockIdx.x * 128;
    const int tid  = threadIdx.x;
    const int w    = tid >> 6, l = tid & 63;
    const int cl   = l & 15;
    const int kb   = (l >> 4) * 8;

    for (int i = tid; i < 64 * 16; i += 256) {
        const int c = i >> 4, ch = i & 15;
        const uint4 v = *reinterpret_cast<const uint4*>(&WT[(size_t)(col0 + c) * 128 + ch * 8]);
        *reinterpret_cast<uint4*>(&WT_lds[c][ch * 8]) = v;
    }
    __syncthreads();

    const int mrow = row0 + w * 32 + cl;
    const int rA0 = mrow < M ? mrow : M - 1;
    const int rA1 = (mrow + 16) < M ? (mrow + 16) : M - 1;
    const uint16_t* a0p = A + (size_t)rA0 * 128 + kb;
    const uint16_t* a1p = A + (size_t)rA1 * 128 + kb;

    f32x4 acc[2][4] = {};
#pragma unroll
    for (int ks = 0; ks < 4; ++ks) {
        const bf16x8 a0 = *reinterpret_cast<const bf16x8*>(a0p + ks * 32);
        const bf16x8 a1 = *reinterpret_cast<const bf16x8*>(a1p + ks * 32);
#pragma unroll
        for (int n = 0; n < 4; ++n) {
            const bf16x8 b = *reinterpret_cast<const bf16x8*>(&WT_lds[n * 16 + cl][ks * 32 + kb]);
            acc[0][n] = __builtin_amdgcn_mfma_f32_16x16x32_bf16(a0, b, acc[0][n], 0, 0, 0);
            acc[1][n] = __builtin_amdgcn_mfma_f32_16x16x32_bf16(a1, b, acc[1][n], 0, 0, 0);
        }
    }

    const int rbase = row0 + w * 32 + (l >> 4) * 4;   // C/D: col=lane&15 [m89]
#pragma unroll
    for (int m = 0; m < 2; ++m) {
#pragma unroll
        for (int n = 0; n < 4; ++n) {
            const int col = col0 + n * 16 + cl;
            const float bv = bias[col];
#pragma unroll
            for (int j = 0; j < 4; ++j) {
                const int row = rbase + m * 16 + j;
                if (row < M) {
                    const float v = acc[m][n][j] + bv;
                    if constexpr (OUT_BF16)
                        ((uint16_t*)Y)[(size_t)row * 128 + col] = f2bf(v);
                    else
                        ((float*)Y)[(size_t)row * 128 + col] = v;
                }
            }
        }
    }
}

// ---- CSR build ----------------------------------------------------------
__global__ __launch_bounds__(256) void hist_kernel(const int* __restrict__ dst, int E,
                                                   int* __restrict__ count)
{
    for (int i = blockIdx.x * blockDim.x + threadIdx.x; i < E;
         i += gridDim.x * blockDim.x)
        atomicAdd(&count[dst[i]], 1);
}

// A: per-1024-block sums of (count[i]+1)
__global__ __launch_bounds__(256) void scan_blocksums(const int* __restrict__ count,
                                                      int* __restrict__ bsum, int N)
{
    __shared__ int wsum[4];
    const int tid = threadIdx.x, lane = tid & 63, w = tid >> 6;
    const int base = blockIdx.x * 1024 + tid * 4;
    int s = 0;
#pragma unroll
    for (int j = 0; j < 4; ++j) {
        int idx = base + j;
        s += (idx < N) ? (count[idx] + 1) : 0;
    }
#pragma unroll
    for (int off = 1; off < 64; off <<= 1) s += __shfl_xor(s, off);
    if (lane == 0) wsum[w] = s;
    __syncthreads();
    if (tid == 0) bsum[blockIdx.x] = wsum[0] + wsum[1] + wsum[2] + wsum[3];
}

// B: one wave scans nb (<=64) block sums -> exclusive bpre; writes offset[N]
__global__ __launch_bounds__(64) void scan_mid(const int* __restrict__ bsum,
                                               int* __restrict__ bpre,
                                               int* __restrict__ offset, int nb, int N)
{
    const int tid = threadIdx.x;
    int v = (tid < nb) ? bsum[tid] : 0;
    int x = v;
#pragma unroll
    for (int off = 1; off < 64; off <<= 1) {
        int y = __shfl_up(x, off);
        if (tid >= off) x += y;
    }
    if (tid < nb) bpre[tid] = x - v;
    const int total = __shfl(x, 63);
    if (tid == 0) offset[N] = total;
}

// C: per-block rescan + apply prefix; writes offset[] and cursor[]
__global__ __launch_bounds__(256) void scan_apply(const int* __restrict__ count,
                                                  const int* __restrict__ bpre,
                                                  int* __restrict__ offset,
                                                  int* __restrict__ cursor, int N)
{
    __shared__ int wsum[4];
    const int tid = threadIdx.x, lane = tid & 63, w = tid >> 6;
    const int base = blockIdx.x * 1024 + tid * 4;
    int v[4];
    int s = 0;
#pragma unroll
    for (int j = 0; j < 4; ++j) {
        int idx = base + j;
        v[j] = (idx < N) ? (count[idx] + 1) : 0;
        s += v[j];
    }
    int x = s;
#pragma unroll
    for (int off = 1; off < 64; off <<= 1) {
        int y = __shfl_up(x, off);
        if (lane >= off) x += y;
    }
    if (lane == 63) wsum[w] = x;
    __syncthreads();
    int wpre = 0;
#pragma unroll
    for (int k = 0; k < 4; ++k) wpre += (k < w) ? wsum[k] : 0;
    int run = bpre[blockIdx.x] + wpre + (x - s);
#pragma unroll
    for (int j = 0; j < 4; ++j) {
        int idx = base + j;
        if (idx < N) { offset[idx] = run; cursor[idx] = run; }
        run += v[j];
    }
}

// scatter edges + self-loops (order within a segment is irrelevant)
__global__ __launch_bounds__(256) void scatter_kernel(const int* __restrict__ src,
                                                      const int* __restrict__ dst,
                                                      int E, int Etot,
                                                      int* __restrict__ cursor,
                                                      int* __restrict__ srcids)
{
    for (int i = blockIdx.x * blockDim.x + threadIdx.x; i < Etot;
         i += gridDim.x * blockDim.x) {
        if (i < E) {
            int p = atomicAdd(&cursor[dst[i]], 1);
            srcids[p] = src[i];
        } else {
            int n = i - E;
            int p = atomicAdd(&cursor[n], 1);
            srcids[p] = n;
        }
    }
}

// ---- Fused per-node aggregation: one wave per node, 4-edge ILP ----------
template <int HEADS, bool ELU, bool OUT_BF16>
__global__ __launch_bounds__(256) void gat_aggregate(
    const uint32_t* __restrict__ xl2,   // [N][64] packed bf16 pairs
    const float* __restrict__ xr,
    const int* __restrict__ offset, const int* __restrict__ srcids,
    const float* __restrict__ att, const float* __restrict__ bias,
    void* __restrict__ out, int N)
{
    const int wid  = (blockIdx.x * blockDim.x + threadIdx.x) >> 6;
    const int lane = threadIdx.x & 63;
    if (wid >= N) return;

    const int f0 = lane * 2;
    const float2 rr = *reinterpret_cast<const float2*>(&xr[(size_t)wid * 128 + f0]);
    const float av0 = att[f0], av1 = att[f0 + 1];
    constexpr int LIM = (HEADS == 4) ? 16 : 64;

    float acc0 = 0.0f, acc1 = 0.0f, d = 0.0f;
    const int beg = offset[wid], end = offset[wid + 1];

    int i = beg;
    for (; i + 4 <= end; i += 4) {            // four independent chains
        int s[4]; uint32_t v[4];
#pragma unroll
        for (int c = 0; c < 4; ++c) s[c] = srcids[i + c];
#pragma unroll
        for (int c = 0; c < 4; ++c) v[c] = xl2[(size_t)s[c] * 64 + lane];
        float a0[4], a1[4], wv[4];
#pragma unroll
        for (int c = 0; c < 4; ++c) {
            a0[c] = __uint_as_float(v[c] << 16);
            a1[c] = __uint_as_float(v[c] & 0xFFFF0000u);
            float t0 = a0[c] + rr.x, t1 = a1[c] + rr.y;
            t0 = t0 > 0.0f ? t0 : 0.2f * t0;
            t1 = t1 > 0.0f ? t1 : 0.2f * t1;
            wv[c] = t0 * av0 + t1 * av1;
        }
#pragma unroll
        for (int off = 1; off < LIM; off <<= 1) {
#pragma unroll
            for (int c = 0; c < 4; ++c) wv[c] += __shfl_xor(wv[c], off);
        }
#pragma unroll
        for (int c = 0; c < 4; ++c) {
            const float p = __expf(wv[c]);
            acc0 += a0[c] * p; acc1 += a1[c] * p; d += p;
        }
    }
    for (; i < end; ++i) {                     // tail 0-3 edges
        const int s = srcids[i];
        const uint32_t v = xl2[(size_t)s * 64 + lane];
        const float a0 = __uint_as_float(v << 16);
        const float a1 = __uint_as_float(v & 0xFFFF0000u);
        float t0 = a0 + rr.x, t1 = a1 + rr.y;
        t0 = t0 > 0.0f ? t0 : 0.2f * t0;
        t1 = t1 > 0.0f ? t1 : 0.2f * t1;
        float w = t0 * av0 + t1 * av1;
#pragma unroll
        for (int off = 1; off < LIM; off <<= 1) w += __shfl_xor(w, off);
        const float p = __expf(w);
        acc0 += a0 * p; acc1 += a1 * p; d += p;
    }

    float v0 = acc0 / d + bias[f0];
    float v1 = acc1 / d + bias[f0 + 1];
    if (ELU) {
        v0 = v0 > 0.0f ? v0 : expm1f(v0);
        v1 = v1 > 0.0f ? v1 : expm1f(v1);
    }
    if constexpr (OUT_BF16) {
        const uint32_t pk = (uint32_t)f2bf(v0) | ((uint32_t)f2bf(v1) << 16);
        ((uint32_t*)out)[(size_t)wid * 64 + lane] = pk;
    } else {
        float2 o = { v0, v1 };
        *reinterpret_cast<float2*>(&((float*)out)[(size_t)wid * 128 + f0]) = o;
    }
}

// ---------------------------------------------------------------------------
extern "C" void kernel_launch(void* const* d_in, const int* in_sizes, int n_in,
                              void* d_out, int out_size, void* d_ws, size_t ws_size,
                              hipStream_t stream)
{
    const float* x     = (const float*)d_in[0];
    const int*   ei    = (const int*)  d_in[1];
    const float* W1l   = (const float*)d_in[2];
    const float* b1l   = (const float*)d_in[3];
    const float* W1r   = (const float*)d_in[4];
    const float* b1r   = (const float*)d_in[5];
    const float* att1  = (const float*)d_in[6];
    const float* bias1 = (const float*)d_in[7];
    const float* W2l   = (const float*)d_in[8];
    const float* b2l   = (const float*)d_in[9];
    const float* W2r   = (const float*)d_in[10];
    const float* b2r   = (const float*)d_in[11];
    const float* att2  = (const float*)d_in[12];
    const float* bias2 = (const float*)d_in[13];
    float* out = (float*)d_out;

    const int N    = in_sizes[0] / 128;
    const int E    = in_sizes[1] / 2;
    const int Etot = E + N;
    const int* srcp = ei;
    const int* dstp = ei + E;
    const int nb = (N + 1023) / 1024;         // <= 64 for N <= 65536

    // ---- workspace layout ------------------------------------------------
    int* count  = (int*)d_ws;                 // [N]
    int* offset = count + N;                  // [N+1]
    int* cursor = offset + N + 1;             // [N]
    int* bsum   = cursor + N;                 // [64]
    int* bpre   = bsum + 64;                  // [64]
    int* srcids = bpre + 64;                  // [Etot]
    size_t int_elems = (size_t)3 * N + 129 + Etot;
    int_elems = (int_elems + 3) & ~(size_t)3;
    uint32_t* base32 = (uint32_t*)d_ws + int_elems;
    uint16_t* x_bf   = (uint16_t*)base32;              // [N*128] bf16
    uint16_t* wt1l   = x_bf + (size_t)N * 128;         // [128*128] each
    uint16_t* wt1r   = wt1l + 128 * 128;
    uint16_t* wt2l   = wt1r + 128 * 128;
    uint16_t* wt2r   = wt2l + 128 * 128;
    float*    xr     = (float*)(wt2r + 128 * 128);     // [N*128] f32
    uint16_t* h_bf   = (uint16_t*)(xr + (size_t)N * 128);  // [N*128] bf16
    uint16_t* xl_bf  = h_bf + (size_t)N * 128;         // [N*128] bf16
    uint32_t* xl2 = (uint32_t*)xl_bf;

    // ---- converts --------------------------------------------------------
    f32_to_bf16<<<(N * 32 + 255) / 256, 256, 0, stream>>>(x, x_bf, N * 32);
    w4_to_bf16T<<<256, 256, 0, stream>>>(W1l, W1r, W2l, W2r,
                                         wt1l, wt1r, wt2l, wt2r);

    // ---- build CSR by dst (parallel scan; self-loops fused in scatter) ----
    hipMemsetAsync(count, 0, (size_t)N * sizeof(int), stream);
    hist_kernel<<<2048, 256, 0, stream>>>(dstp, E, count);
    scan_blocksums<<<nb, 256, 0, stream>>>(count, bsum, N);
    scan_mid<<<1, 64, 0, stream>>>(bsum, bpre, offset, nb, N);
    scan_apply<<<nb, 256, 0, stream>>>(count, bpre, offset, cursor, N);
    scatter_kernel<<<2048, 256, 0, stream>>>(srcp, dstp, E, Etot, cursor, srcids);

    dim3 gG((N + 127) / 128, 2);
    const int ablocks = (N + 3) / 4;

    // ---- layer 1 ----
    gemm_mfma<true ><<<gG, 256, 0, stream>>>(x_bf, wt1l, b1l, xl_bf, N);
    gemm_mfma<false><<<gG, 256, 0, stream>>>(x_bf, wt1r, b1r, xr,    N);
    gat_aggregate<4, true, true><<<ablocks, 256, 0, stream>>>(
        xl2, xr, offset, srcids, att1, bias1, h_bf, N);
    // ---- layer 2 ----
    gemm_mfma<true ><<<gG, 256, 0, stream>>>(h_bf, wt2l, b2l, xl_bf, N);
    gemm_mfma<false><<<gG, 256, 0, stream>>>(h_bf, wt2r, b2r, xr,    N);
    gat_aggregate<1, false, false><<<ablocks, 256, 0, stream>>>(
        xl2, xr, offset, srcids, att2, bias2, out, N);
}

// Round 15
// 376.861 us; speedup vs baseline: 16.1800x; 1.0189x over previous
//
#include <hip/hip_runtime.h>
#include <hip/hip_bf16.h>
#include <cstdint>

// ---------------------------------------------------------------------------
// GATv2 encoder. Per launch:
//   convert x->bf16, W*->bf16T; CSR by dst via parallel scan;
//   layer: 1x dual MFMA GEMM (xl bf16 + xr f32 in one dispatch)
//          -> one-wave-per-node aggregate (8-edge ILP, split idx/gather loads)
// Softmax max-subtraction dropped (cancels algebraically; logits are tiny).
// ---------------------------------------------------------------------------

typedef __attribute__((ext_vector_type(8))) short  bf16x8;
typedef __attribute__((ext_vector_type(4))) float  f32x4;

__device__ inline uint16_t f2bf(float x) {
    union { __hip_bfloat16 b; uint16_t u; } cv;
    cv.b = __float2bfloat16(x);
    return cv.u;
}

// ---- converts -----------------------------------------------------------
__global__ __launch_bounds__(256) void f32_to_bf16(const float* __restrict__ in,
                                                   uint16_t* __restrict__ outp, int n4)
{
    int i = blockIdx.x * blockDim.x + threadIdx.x;
    if (i < n4) {
        float4 v = reinterpret_cast<const float4*>(in)[i];
        ushort4 o = { f2bf(v.x), f2bf(v.y), f2bf(v.z), f2bf(v.w) };
        reinterpret_cast<ushort4*>(outp)[i] = o;
    }
}

__global__ __launch_bounds__(256) void w4_to_bf16T(
    const float* __restrict__ W0, const float* __restrict__ W1,
    const float* __restrict__ W2, const float* __restrict__ W3,
    uint16_t* __restrict__ T0, uint16_t* __restrict__ T1,
    uint16_t* __restrict__ T2, uint16_t* __restrict__ T3)
{
    int i = blockIdx.x * blockDim.x + threadIdx.x;
    const int which = i >> 14, j = i & 16383;
    const int k = j >> 7, c = j & 127;
    const float* W = which == 0 ? W0 : which == 1 ? W1 : which == 2 ? W2 : W3;
    uint16_t*   T = which == 0 ? T0 : which == 1 ? T1 : which == 2 ? T2 : T3;
    T[c * 128 + k] = f2bf(W[j]);
}

// ---- Dual MFMA GEMM: one dispatch does A@Wl -> Yl(bf16) and A@Wr -> Yr(f32)
// grid (ceil(M/128), 4): y<2 -> left half, y>=2 -> right half; col0=(y&1)*64
__global__ __launch_bounds__(256) void gemm_mfma_dual(
    const uint16_t* __restrict__ A,
    const uint16_t* __restrict__ WTl, const uint16_t* __restrict__ WTr,
    const float* __restrict__ biasl, const float* __restrict__ biasr,
    uint16_t* __restrict__ Yl, float* __restrict__ Yr, int M)
{
    __shared__ uint16_t WT_lds[64][136];          // 17408 B, pad->272B rows
    const int half = blockIdx.y >> 1;             // 0 = l/bf16, 1 = r/f32
    const int col0 = (blockIdx.y & 1) * 64;
    const int row0 = blockIdx.x * 128;
    const uint16_t* WT   = half ? WTr   : WTl;
    const float*    bias = half ? biasr : biasl;
    const int tid  = threadIdx.x;
    const int w    = tid >> 6, l = tid & 63;
    const int cl   = l & 15;
    const int kb   = (l >> 4) * 8;

    for (int i = tid; i < 64 * 16; i += 256) {
        const int c = i >> 4, ch = i & 15;
        const uint4 v = *reinterpret_cast<const uint4*>(&WT[(size_t)(col0 + c) * 128 + ch * 8]);
        *reinterpret_cast<uint4*>(&WT_lds[c][ch * 8]) = v;
    }
    __syncthreads();

    const int mrow = row0 + w * 32 + cl;
    const int rA0 = mrow < M ? mrow : M - 1;
    const int rA1 = (mrow + 16) < M ? (mrow + 16) : M - 1;
    const uint16_t* a0p = A + (size_t)rA0 * 128 + kb;
    const uint16_t* a1p = A + (size_t)rA1 * 128 + kb;

    f32x4 acc[2][4] = {};
#pragma unroll
    for (int ks = 0; ks < 4; ++ks) {
        const bf16x8 a0 = *reinterpret_cast<const bf16x8*>(a0p + ks * 32);
        const bf16x8 a1 = *reinterpret_cast<const bf16x8*>(a1p + ks * 32);
#pragma unroll
        for (int n = 0; n < 4; ++n) {
            const bf16x8 b = *reinterpret_cast<const bf16x8*>(&WT_lds[n * 16 + cl][ks * 32 + kb]);
            acc[0][n] = __builtin_amdgcn_mfma_f32_16x16x32_bf16(a0, b, acc[0][n], 0, 0, 0);
            acc[1][n] = __builtin_amdgcn_mfma_f32_16x16x32_bf16(a1, b, acc[1][n], 0, 0, 0);
        }
    }

    const int rbase = row0 + w * 32 + (l >> 4) * 4;   // C/D: col=lane&15 [m89]
#pragma unroll
    for (int m = 0; m < 2; ++m) {
#pragma unroll
        for (int n = 0; n < 4; ++n) {
            const int col = col0 + n * 16 + cl;
            const float bv = bias[col];
#pragma unroll
            for (int j = 0; j < 4; ++j) {
                const int row = rbase + m * 16 + j;
                if (row < M) {
                    const float v = acc[m][n][j] + bv;
                    if (half == 0)
                        Yl[(size_t)row * 128 + col] = f2bf(v);
                    else
                        Yr[(size_t)row * 128 + col] = v;
                }
            }
        }
    }
}

// ---- CSR build ----------------------------------------------------------
__global__ __launch_bounds__(256) void hist_kernel(const int* __restrict__ dst, int E,
                                                   int* __restrict__ count)
{
    for (int i = blockIdx.x * blockDim.x + threadIdx.x; i < E;
         i += gridDim.x * blockDim.x)
        atomicAdd(&count[dst[i]], 1);
}

__global__ __launch_bounds__(256) void scan_blocksums(const int* __restrict__ count,
                                                      int* __restrict__ bsum, int N)
{
    __shared__ int wsum[4];
    const int tid = threadIdx.x, lane = tid & 63, w = tid >> 6;
    const int base = blockIdx.x * 1024 + tid * 4;
    int s = 0;
#pragma unroll
    for (int j = 0; j < 4; ++j) {
        int idx = base + j;
        s += (idx < N) ? (count[idx] + 1) : 0;
    }
#pragma unroll
    for (int off = 1; off < 64; off <<= 1) s += __shfl_xor(s, off);
    if (lane == 0) wsum[w] = s;
    __syncthreads();
    if (tid == 0) bsum[blockIdx.x] = wsum[0] + wsum[1] + wsum[2] + wsum[3];
}

__global__ __launch_bounds__(64) void scan_mid(const int* __restrict__ bsum,
                                               int* __restrict__ bpre,
                                               int* __restrict__ offset, int nb, int N)
{
    const int tid = threadIdx.x;
    int v = (tid < nb) ? bsum[tid] : 0;
    int x = v;
#pragma unroll
    for (int off = 1; off < 64; off <<= 1) {
        int y = __shfl_up(x, off);
        if (tid >= off) x += y;
    }
    if (tid < nb) bpre[tid] = x - v;
    const int total = __shfl(x, 63);
    if (tid == 0) offset[N] = total;
}

__global__ __launch_bounds__(256) void scan_apply(const int* __restrict__ count,
                                                  const int* __restrict__ bpre,
                                                  int* __restrict__ offset,
                                                  int* __restrict__ cursor, int N)
{
    __shared__ int wsum[4];
    const int tid = threadIdx.x, lane = tid & 63, w = tid >> 6;
    const int base = blockIdx.x * 1024 + tid * 4;
    int v[4];
    int s = 0;
#pragma unroll
    for (int j = 0; j < 4; ++j) {
        int idx = base + j;
        v[j] = (idx < N) ? (count[idx] + 1) : 0;
        s += v[j];
    }
    int x = s;
#pragma unroll
    for (int off = 1; off < 64; off <<= 1) {
        int y = __shfl_up(x, off);
        if (lane >= off) x += y;
    }
    if (lane == 63) wsum[w] = x;
    __syncthreads();
    int wpre = 0;
#pragma unroll
    for (int k = 0; k < 4; ++k) wpre += (k < w) ? wsum[k] : 0;
    int run = bpre[blockIdx.x] + wpre + (x - s);
#pragma unroll
    for (int j = 0; j < 4; ++j) {
        int idx = base + j;
        if (idx < N) { offset[idx] = run; cursor[idx] = run; }
        run += v[j];
    }
}

__global__ __launch_bounds__(256) void scatter_kernel(const int* __restrict__ src,
                                                      const int* __restrict__ dst,
                                                      int E, int Etot,
                                                      int* __restrict__ cursor,
                                                      int* __restrict__ srcids)
{
    for (int i = blockIdx.x * blockDim.x + threadIdx.x; i < Etot;
         i += gridDim.x * blockDim.x) {
        if (i < E) {
            int p = atomicAdd(&cursor[dst[i]], 1);
            srcids[p] = src[i];
        } else {
            int n = i - E;
            int p = atomicAdd(&cursor[n], 1);
            srcids[p] = n;
        }
    }
}

// ---- Aggregate batch helper: B independent gather->reduce->exp chains ----
template <int B, int LIM>
__device__ inline void agg_batch(const uint32_t* __restrict__ xl2,
                                 const int* __restrict__ srcids, int i, int lane,
                                 float2 rr, float av0, float av1,
                                 float& acc0, float& acc1, float& d)
{
    int s[B];
#pragma unroll
    for (int c = 0; c < B; ++c) s[c] = srcids[i + c];     // indices first (MLP)
    float a0[B], a1[B], wv[B];
#pragma unroll
    for (int c = 0; c < B; ++c) {
        const uint32_t v = xl2[(size_t)s[c] * 64 + lane];
        a0[c] = __uint_as_float(v << 16);
        a1[c] = __uint_as_float(v & 0xFFFF0000u);
        float t0 = a0[c] + rr.x, t1 = a1[c] + rr.y;
        t0 = t0 > 0.0f ? t0 : 0.2f * t0;
        t1 = t1 > 0.0f ? t1 : 0.2f * t1;
        wv[c] = t0 * av0 + t1 * av1;
    }
#pragma unroll
    for (int off = 1; off < LIM; off <<= 1) {
#pragma unroll
        for (int c = 0; c < B; ++c) wv[c] += __shfl_xor(wv[c], off);
    }
#pragma unroll
    for (int c = 0; c < B; ++c) {
        const float p = __expf(wv[c]);
        acc0 += a0[c] * p; acc1 += a1[c] * p; d += p;
    }
}

// ---- Fused per-node aggregation: one wave per node, 8/4/1-edge ILP ------
template <int HEADS, bool ELU, bool OUT_BF16>
__global__ __launch_bounds__(256) void gat_aggregate(
    const uint32_t* __restrict__ xl2,   // [N][64] packed bf16 pairs
    const float* __restrict__ xr,
    const int* __restrict__ offset, const int* __restrict__ srcids,
    const float* __restrict__ att, const float* __restrict__ bias,
    void* __restrict__ out, int N)
{
    const int wid  = (blockIdx.x * blockDim.x + threadIdx.x) >> 6;
    const int lane = threadIdx.x & 63;
    if (wid >= N) return;

    const int f0 = lane * 2;
    const float2 rr = *reinterpret_cast<const float2*>(&xr[(size_t)wid * 128 + f0]);
    const float av0 = att[f0], av1 = att[f0 + 1];
    constexpr int LIM = (HEADS == 4) ? 16 : 64;

    float acc0 = 0.0f, acc1 = 0.0f, d = 0.0f;
    const int beg = offset[wid], end = offset[wid + 1];

    int i = beg;
    for (; i + 8 <= end; i += 8)
        agg_batch<8, LIM>(xl2, srcids, i, lane, rr, av0, av1, acc0, acc1, d);
    if (i + 4 <= end) {
        agg_batch<4, LIM>(xl2, srcids, i, lane, rr, av0, av1, acc0, acc1, d);
        i += 4;
    }
    for (; i < end; ++i)
        agg_batch<1, LIM>(xl2, srcids, i, lane, rr, av0, av1, acc0, acc1, d);

    float v0 = acc0 / d + bias[f0];
    float v1 = acc1 / d + bias[f0 + 1];
    if (ELU) {
        v0 = v0 > 0.0f ? v0 : expm1f(v0);
        v1 = v1 > 0.0f ? v1 : expm1f(v1);
    }
    if constexpr (OUT_BF16) {
        const uint32_t pk = (uint32_t)f2bf(v0) | ((uint32_t)f2bf(v1) << 16);
        ((uint32_t*)out)[(size_t)wid * 64 + lane] = pk;
    } else {
        float2 o = { v0, v1 };
        *reinterpret_cast<float2*>(&((float*)out)[(size_t)wid * 128 + f0]) = o;
    }
}

// ---------------------------------------------------------------------------
extern "C" void kernel_launch(void* const* d_in, const int* in_sizes, int n_in,
                              void* d_out, int out_size, void* d_ws, size_t ws_size,
                              hipStream_t stream)
{
    const float* x     = (const float*)d_in[0];
    const int*   ei    = (const int*)  d_in[1];
    const float* W1l   = (const float*)d_in[2];
    const float* b1l   = (const float*)d_in[3];
    const float* W1r   = (const float*)d_in[4];
    const float* b1r   = (const float*)d_in[5];
    const float* att1  = (const float*)d_in[6];
    const float* bias1 = (const float*)d_in[7];
    const float* W2l   = (const float*)d_in[8];
    const float* b2l   = (const float*)d_in[9];
    const float* W2r   = (const float*)d_in[10];
    const float* b2r   = (const float*)d_in[11];
    const float* att2  = (const float*)d_in[12];
    const float* bias2 = (const float*)d_in[13];
    float* out = (float*)d_out;

    const int N    = in_sizes[0] / 128;
    const int E    = in_sizes[1] / 2;
    const int Etot = E + N;
    const int* srcp = ei;
    const int* dstp = ei + E;
    const int nb = (N + 1023) / 1024;         // <= 64 for N <= 65536

    // ---- workspace layout ------------------------------------------------
    int* count  = (int*)d_ws;                 // [N]
    int* offset = count + N;                  // [N+1]
    int* cursor = offset + N + 1;             // [N]
    int* bsum   = cursor + N;                 // [64]
    int* bpre   = bsum + 64;                  // [64]
    int* srcids = bpre + 64;                  // [Etot]
    size_t int_elems = (size_t)3 * N + 129 + Etot;
    int_elems = (int_elems + 3) & ~(size_t)3;
    uint32_t* base32 = (uint32_t*)d_ws + int_elems;
    uint16_t* x_bf   = (uint16_t*)base32;              // [N*128] bf16
    uint16_t* wt1l   = x_bf + (size_t)N * 128;         // [128*128] each
    uint16_t* wt1r   = wt1l + 128 * 128;
    uint16_t* wt2l   = wt1r + 128 * 128;
    uint16_t* wt2r   = wt2l + 128 * 128;
    float*    xr     = (float*)(wt2r + 128 * 128);     // [N*128] f32
    uint16_t* h_bf   = (uint16_t*)(xr + (size_t)N * 128);  // [N*128] bf16
    uint16_t* xl_bf  = h_bf + (size_t)N * 128;         // [N*128] bf16
    uint32_t* xl2 = (uint32_t*)xl_bf;

    // ---- converts --------------------------------------------------------
    f32_to_bf16<<<(N * 32 + 255) / 256, 256, 0, stream>>>(x, x_bf, N * 32);
    w4_to_bf16T<<<256, 256, 0, stream>>>(W1l, W1r, W2l, W2r,
                                         wt1l, wt1r, wt2l, wt2r);

    // ---- build CSR by dst (parallel scan; self-loops fused in scatter) ----
    hipMemsetAsync(count, 0, (size_t)N * sizeof(int), stream);
    hist_kernel<<<2048, 256, 0, stream>>>(dstp, E, count);
    scan_blocksums<<<nb, 256, 0, stream>>>(count, bsum, N);
    scan_mid<<<1, 64, 0, stream>>>(bsum, bpre, offset, nb, N);
    scan_apply<<<nb, 256, 0, stream>>>(count, bpre, offset, cursor, N);
    scatter_kernel<<<2048, 256, 0, stream>>>(srcp, dstp, E, Etot, cursor, srcids);

    dim3 gG((N + 127) / 128, 4);
    const int ablocks = (N + 3) / 4;

    // ---- layer 1 ----
    gemm_mfma_dual<<<gG, 256, 0, stream>>>(x_bf, wt1l, wt1r, b1l, b1r,
                                           xl_bf, xr, N);
    gat_aggregate<4, true, true><<<ablocks, 256, 0, stream>>>(
        xl2, xr, offset, srcids, att1, bias1, h_bf, N);
    // ---- layer 2 ----
    gemm_mfma_dual<<<gG, 256, 0, stream>>>(h_bf, wt2l, wt2r, b2l, b2r,
                                           xl_bf, xr, N);
    gat_aggregate<1, false, false><<<ablocks, 256, 0, stream>>>(
        xl2, xr, offset, srcids, att2, bias2, out, N);
}